// Round 2
// baseline (283.393 us; speedup 1.0000x reference)
//
#include <hip/hip_runtime.h>
#include <hip/hip_bf16.h>

#define D 128
#define EPSV 1e-5f

static inline int cdiv(int a, int b) { return (a + b - 1) / b; }

typedef __attribute__((ext_vector_type(8))) short short8v;
typedef __attribute__((ext_vector_type(4))) float floatx4;

// bf16 RNE pack / unpack helpers
__device__ __forceinline__ unsigned short f2bf(float f) {
    unsigned int x = __float_as_uint(f);
    unsigned int r = x + 0x7fffu + ((x >> 16) & 1u);
    return (unsigned short)(r >> 16);
}
__device__ __forceinline__ float bflo(unsigned int u) { return __uint_as_float(u << 16); }
__device__ __forceinline__ float bfhi(unsigned int u) {
    return __uint_as_float(u & 0xffff0000u);
}

// ---------------- W -> bf16 transposed + cnt zeroing (once per launch) ----------------

__global__ void prep_w(const float* __restrict__ W1, const float* __restrict__ W2,
                       unsigned short* __restrict__ WT1, unsigned short* __restrict__ WT2,
                       int* __restrict__ cnt, int N) {
    int b = blockIdx.x;
    const float* W = (b < D) ? W1 : W2;
    unsigned short* WT = (b < D) ? WT1 : WT2;
    int k = b & (D - 1);
    int n = threadIdx.x;
    WT[n * D + k] = f2bf(W[k * D + n]);
    int gid = b * D + n;
    for (int i = gid; i < N; i += 2 * D * D) cnt[i] = 0;
}

// ---------------- edge preprocessing (fully deterministic) ----------------

__global__ void hist_rank_kernel(const int* __restrict__ col, int* __restrict__ cnt,
                                 int* __restrict__ rank, int E_) {
    int e = blockIdx.x * blockDim.x + threadIdx.x;
    if (e >= E_) return;
    rank[e] = atomicAdd(&cnt[col[e]], 1);
}

// fused exclusive scan: each block recomputes its chunk prefix directly (nb ~ 49,
// redundant reads are ~10 MB total -> trivial; saves one dispatch + bsum buffer).
// Integer arithmetic -> bit-identical offs vs the two-kernel version.
__global__ void scan_kernel(const int* __restrict__ cnt, int* __restrict__ offs, int n,
                            int E_) {
    __shared__ int sm[1024];
    __shared__ int sbo_s;
    int tid = threadIdx.x;
    int lim = blockIdx.x * 1024;
    int pre = 0;
    for (int i = tid; i < lim; i += 1024) pre += cnt[i];
    sm[tid] = pre;
    __syncthreads();
    for (int off = 512; off > 0; off >>= 1) {
        if (tid < off) sm[tid] += sm[tid + off];
        __syncthreads();
    }
    if (tid == 0) {
        sbo_s = sm[0];
        if (blockIdx.x == 0) offs[n] = E_;
    }
    __syncthreads();
    int i = lim + tid;
    int v = (i < n) ? cnt[i] : 0;
    sm[tid] = v;
    __syncthreads();
    for (int off = 1; off < 1024; off <<= 1) {
        int t = (tid >= off) ? sm[tid - off] : 0;
        __syncthreads();
        sm[tid] += t;
        __syncthreads();
    }
    if (i < n) offs[i] = sm[tid] - v + sbo_s;
}

// scatter packed (src_row<<32 | ea_bits) into CSR slot offs[col]+rank.
__global__ void scatter_pack(const int* __restrict__ row, const int* __restrict__ col,
                             const float* __restrict__ ea, const int* __restrict__ rank,
                             const int* __restrict__ offs, long long* __restrict__ pk,
                             int E_) {
    int e = blockIdx.x * blockDim.x + threadIdx.x;
    if (e >= E_) return;
    int p = offs[col[e]] + rank[e];
    pk[p] = ((long long)row[e] << 32) | (unsigned int)__float_as_int(ea[e]);
}

// merged kernel: blocks [0,SB) do the per-node bitonic sort (VALU-bound);
// blocks [SB, SB+NB) do the layer-1 BN stats gather (memory-bound).
// Running them in one dispatch overlaps the two pipes and saves a launch.
__global__ __launch_bounds__(256) void sort_bn_kernel(
    const long long* __restrict__ pk, const int* __restrict__ offs,
    float* __restrict__ dis, int2* __restrict__ csr, int n,
    const float* __restrict__ emb, const int* __restrict__ idx,
    float* __restrict__ pS, float* __restrict__ pQ, int SB, int NB) {
    if ((int)blockIdx.x < SB) {
        // ---- sort path (identical numerics to original sort_deg_kernel) ----
        int node = blockIdx.x * 4 + (threadIdx.x >> 6);
        int lane = threadIdx.x & 63;
        if (node >= n) return;
        int p0 = offs[node], p1 = offs[node + 1];
        int deg = p1 - p0;
        if (deg <= 64) {
            long long v = (lane < deg) ? pk[p0 + lane] : 0x7fffffffffffffffLL;
            for (int k = 2; k <= 64; k <<= 1) {
                for (int j = k >> 1; j > 0; j >>= 1) {
                    long long partner = __shfl_xor(v, j, 64);
                    bool up = ((lane & k) == 0);
                    bool keepMin = ((lane & j) == 0);
                    long long mn = v < partner ? v : partner;
                    long long mx = v < partner ? partner : v;
                    v = (up == keepMin) ? mn : mx;
                }
            }
            int r = (int)(v >> 32);
            int eab = (int)(v & 0xffffffffLL);
            if (lane < deg) csr[p0 + lane] = make_int2(r, eab);
            float av = (lane < deg) ? __int_as_float(eab) : 0.f;
            float s = av;
            for (int off = 32; off > 0; off >>= 1) s += __shfl_xor(s, off, 64);
            if (lane == 0) dis[node] = s > 0.f ? rsqrtf(fmaxf(s, EPSV)) : 0.f;
        } else {
            if (lane == 0) {  // deterministic O(d^2) selection fallback (unreachable)
                float dg = 0.f;
                for (int p = p0; p < p1; ++p) {
                    long long best = 0x7fffffffffffffffLL;
                    for (int q2 = p0; q2 < p1; ++q2) {
                        long long cand = pk[q2];
                        int less = 0;
                        for (int q3 = p0; q3 < p1; ++q3)
                            if (pk[q3] < cand) ++less;
                        if (less == p - p0) { best = cand; break; }
                    }
                    int r = (int)(best >> 32);
                    int eab = (int)(best & 0xffffffffLL);
                    csr[p] = make_int2(r, eab);
                    dg += __int_as_float(eab);
                }
                dis[node] = dg > 0.f ? rsqrtf(fmaxf(dg, EPSV)) : 0.f;
            }
        }
        return;
    }
    // ---- bn-stats path (layer 1: emb gather; identical numerics to bn_stats<true>) ----
    int bid = blockIdx.x - SB;
    int sub = threadIdx.x >> 5;
    int q = threadIdx.x & 31;
    float4 s = make_float4(0, 0, 0, 0), s2 = make_float4(0, 0, 0, 0);
    int stride = NB * 8;
    int i = bid * 8 + sub;
    int r_next = (i < n) ? idx[i] : 0;
    for (; i < n; i += stride) {
        int r = r_next;
        int i2 = i + stride;
        if (i2 < n) r_next = idx[i2];
        float4 v = *(const float4*)&emb[(long)r * D + q * 4];
        s.x += v.x; s.y += v.y; s.z += v.z; s.w += v.w;
        s2.x += v.x * v.x; s2.y += v.y * v.y; s2.z += v.z * v.z; s2.w += v.w * v.w;
    }
    __shared__ float4 redA[256], redB[256];
    redA[threadIdx.x] = s;
    redB[threadIdx.x] = s2;
    __syncthreads();
    for (int off = 128; off >= 32; off >>= 1) {
        if (threadIdx.x < off) {
            float4 a = redA[threadIdx.x + off], b = redB[threadIdx.x + off];
            redA[threadIdx.x].x += a.x; redA[threadIdx.x].y += a.y;
            redA[threadIdx.x].z += a.z; redA[threadIdx.x].w += a.w;
            redB[threadIdx.x].x += b.x; redB[threadIdx.x].y += b.y;
            redB[threadIdx.x].z += b.z; redB[threadIdx.x].w += b.w;
        }
        __syncthreads();
    }
    if (threadIdx.x < 32) {
        float4 a = redA[threadIdx.x], b = redB[threadIdx.x];
        int bofs = bid;
        pS[(q * 4 + 0) * NB + bofs] = a.x;
        pS[(q * 4 + 1) * NB + bofs] = a.y;
        pS[(q * 4 + 2) * NB + bofs] = a.z;
        pS[(q * 4 + 3) * NB + bofs] = a.w;
        pQ[(q * 4 + 0) * NB + bofs] = b.x;
        pQ[(q * 4 + 1) * NB + bofs] = b.y;
        pQ[(q * 4 + 2) * NB + bofs] = b.z;
        pQ[(q * 4 + 3) * NB + bofs] = b.w;
    }
}

__global__ __launch_bounds__(256) void bn_reduce(const float* __restrict__ pS,
                                                 const float* __restrict__ pQ, int nb,
                                                 const float* __restrict__ gamma,
                                                 const float* __restrict__ beta,
                                                 float* __restrict__ scale,
                                                 float* __restrict__ shift, float n) {
    int d = blockIdx.x;
    int tid = threadIdx.x;
    float s = 0.f, q = 0.f;
    for (int b = tid; b < nb; b += 256) {
        s += pS[d * nb + b];
        q += pQ[d * nb + b];
    }
    __shared__ float smS[256], smQ[256];
    smS[tid] = s;
    smQ[tid] = q;
    __syncthreads();
    for (int off = 128; off > 0; off >>= 1) {
        if (tid < off) {
            smS[tid] += smS[tid + off];
            smQ[tid] += smQ[tid + off];
        }
        __syncthreads();
    }
    if (tid == 0) {
        float mean = smS[0] / n;
        float var = smQ[0] / n - mean * mean;
        float rstd = rsqrtf(var + EPSV);
        float sc = gamma[d] * rstd;
        scale[d] = sc;
        shift[d] = beta[d] - mean * sc;
    }
}

// ---------------- MFMA GEMM: h' = dis[r] * (bn(src) @ W), out bf16 ----------

template <bool GATHER, bool BF16IN>
__global__ __launch_bounds__(256) void gemm_mfma(const void* __restrict__ srcv,
                                                 const int* __restrict__ idx,
                                                 const float* __restrict__ scale,
                                                 const float* __restrict__ shift,
                                                 const unsigned short* __restrict__ WTb,
                                                 const float* __restrict__ disv,
                                                 unsigned short* __restrict__ outb, int n) {
    __shared__ unsigned short xsb[64 * 136];   // 17.0 KB
    __shared__ unsigned short wsb[128 * 136];  // 34.0 KB (reused as float scratch in epi)
    int tid = threadIdx.x;
    int r0 = blockIdx.x * 64;
    const float4* scale4 = (const float4*)scale;
    const float4* shift4 = (const float4*)shift;
    for (int it = 0; it < 4; ++it) {
        int flat = it * 256 + tid;  // 0..1023
        int r = flat >> 4;
        int c16 = flat & 15;
        int gr = r0 + r;
        float4 v0 = make_float4(0, 0, 0, 0), v1 = make_float4(0, 0, 0, 0);
        if (gr < n) {
            int srow = GATHER ? idx[gr] : gr;
            float4 x0, x1;
            if (BF16IN) {
                const unsigned short* sb = (const unsigned short*)srcv;
                uint4 raw = *(const uint4*)&sb[(long)srow * D + c16 * 8];
                x0 = make_float4(bflo(raw.x), bfhi(raw.x), bflo(raw.y), bfhi(raw.y));
                x1 = make_float4(bflo(raw.z), bfhi(raw.z), bflo(raw.w), bfhi(raw.w));
            } else {
                const float* sf = (const float*)srcv;
                x0 = *(const float4*)&sf[(long)srow * D + c16 * 8];
                x1 = *(const float4*)&sf[(long)srow * D + c16 * 8 + 4];
            }
            float4 sa = scale4[c16 * 2], sb2 = shift4[c16 * 2];
            float4 sc = scale4[c16 * 2 + 1], sd = shift4[c16 * 2 + 1];
            v0 = make_float4(x0.x * sa.x + sb2.x, x0.y * sa.y + sb2.y, x0.z * sa.z + sb2.z,
                             x0.w * sa.w + sb2.w);
            v1 = make_float4(x1.x * sc.x + sd.x, x1.y * sc.y + sd.y, x1.z * sc.z + sd.z,
                             x1.w * sc.w + sd.w);
        }
        int phys = c16 ^ (r & 15);
        ushort4 o0 = make_ushort4(f2bf(v0.x), f2bf(v0.y), f2bf(v0.z), f2bf(v0.w));
        ushort4 o1 = make_ushort4(f2bf(v1.x), f2bf(v1.y), f2bf(v1.z), f2bf(v1.w));
        *(ushort4*)&xsb[r * 136 + phys * 8] = o0;
        *(ushort4*)&xsb[r * 136 + phys * 8 + 4] = o1;
    }
    for (int it = 0; it < 8; ++it) {
        int flat = it * 256 + tid;  // 0..2047
        int nrow = flat >> 4;
        int c16 = flat & 15;
        int phys = c16 ^ (nrow & 15);
        uint4 w = *(const uint4*)&WTb[nrow * D + c16 * 8];
        *(uint4*)&wsb[nrow * 136 + phys * 8] = w;
    }
    __syncthreads();
    int wv = tid >> 6;
    int lane = tid & 63;
    int m = lane & 15, q = lane >> 4;
    int r0w = wv * 16;
    floatx4 acc[8];
#pragma unroll
    for (int t = 0; t < 8; ++t) acc[t] = (floatx4)(0.f);
#pragma unroll
    for (int ks = 0; ks < 4; ++ks) {
        int c16 = ks * 4 + q;
        short8v a = *(short8v*)&xsb[(r0w + m) * 136 + (c16 ^ ((r0w + m) & 15)) * 8];
#pragma unroll
        for (int t = 0; t < 8; ++t) {
            short8v b = *(short8v*)&wsb[(t * 16 + m) * 136 + (c16 ^ m) * 8];
            acc[t] = __builtin_amdgcn_mfma_f32_16x16x32_bf16(a, b, acc[t], 0, 0, 0);
        }
    }
    __syncthreads();
    float* fl = (float*)wsb;  // 64 x 132 floats
#pragma unroll
    for (int t = 0; t < 8; ++t) {
#pragma unroll
        for (int r = 0; r < 4; ++r) {
            fl[(r0w + q * 4 + r) * 132 + t * 16 + m] = acc[t][r];
        }
    }
    __syncthreads();
    for (int it = 0; it < 4; ++it) {
        int c = it * 256 + tid;
        int r = c >> 4;
        int k8 = (c & 15) * 8;
        int gr = r0 + r;
        if (gr < n) {
            float dsc = disv[gr];  // fold dis[row] into h' (removes fill_w)
            float4 v0 = *(float4*)&fl[r * 132 + k8];
            float4 v1 = *(float4*)&fl[r * 132 + k8 + 4];
            ushort4 o0 = make_ushort4(f2bf(v0.x * dsc), f2bf(v0.y * dsc), f2bf(v0.z * dsc),
                                      f2bf(v0.w * dsc));
            ushort4 o1 = make_ushort4(f2bf(v1.x * dsc), f2bf(v1.y * dsc), f2bf(v1.z * dsc),
                                      f2bf(v1.w * dsc));
            *(ushort4*)&outb[(long)gr * D + k8] = o0;
            *(ushort4*)&outb[(long)gr * D + k8 + 4] = o1;
        }
    }
}

// ---------------- aggregation: dual-edge gathers, deep unroll ----------------
// x[c] = relu(b + dis[c] * sum_e ea_e * h'[row_e]); output bf16 (both layers).
// STATS (layer 1) additionally accumulates BN partials.
// NUMERICS NOTE: the even/odd-half partition and the increasing-index accumulation
// order per half are bit-identical to the verified baseline (absmax 2^-9). The only
// change vs baseline is the unroll depth (8 edges in flight per lane instead of 4) —
// the per-half edge sequence (half, half+2, half+4, ...) is unchanged, so sums are
// bit-for-bit identical. Do NOT change the partition (round-1 lesson: 4-way stride
// partition pushed absmax to 6.8e-3 > 4.4e-3 threshold).

template <bool STATS>
__global__ __launch_bounds__(256) void agg_kernel(const uint2* __restrict__ hw2,
                                                  const int2* __restrict__ csr,
                                                  const int* __restrict__ offs,
                                                  const float* __restrict__ dis,
                                                  const float4* __restrict__ bias4,
                                                  unsigned short* __restrict__ xoutb, int n,
                                                  float* __restrict__ pS,
                                                  float* __restrict__ pQ, int NB) {
    int lane = threadIdx.x & 63;
    int wv = threadIdx.x >> 6;
    int half = lane >> 5;
    int fl = lane & 31;
    float4 bs = bias4[fl];
    float4 s = make_float4(0.f, 0.f, 0.f, 0.f), s2 = make_float4(0.f, 0.f, 0.f, 0.f);
    int nGroups = (n + 3) >> 2;
    for (int grp = blockIdx.x; grp < nGroups; grp += gridDim.x) {
        int node = grp * 4 + wv;
        if (node < n) {
            int p0 = offs[node], p1 = offs[node + 1];
            float dc = dis[node];
            float4 acc = make_float4(0.f, 0.f, 0.f, 0.f);
            for (int base = p0; base < p1; base += 64) {
                int cnt = p1 - base;
                if (cnt > 64) cnt = 64;
                int2 e = csr[base + (lane < cnt ? lane : cnt - 1)];
                for (int j = 0; j < cnt; j += 16) {
#pragma unroll
                    for (int u = 0; u < 8; ++u) {
                        int jj = j + 2 * u + half;
                        bool ok = jj < cnt;
                        int sel = ok ? jj : 0;
                        int r = __shfl(e.x, sel, 64);
                        float w = ok ? __int_as_float(__shfl(e.y, sel, 64)) : 0.f;
                        uint2 uu = hw2[(long)r * 32 + fl];
                        acc.x += w * bflo(uu.x);
                        acc.y += w * bfhi(uu.x);
                        acc.z += w * bflo(uu.y);
                        acc.w += w * bfhi(uu.y);
                    }
                }
            }
            acc.x += __shfl_xor(acc.x, 32, 64);
            acc.y += __shfl_xor(acc.y, 32, 64);
            acc.z += __shfl_xor(acc.z, 32, 64);
            acc.w += __shfl_xor(acc.w, 32, 64);
            float4 x = make_float4(fmaxf(bs.x + dc * acc.x, 0.f), fmaxf(bs.y + dc * acc.y, 0.f),
                                   fmaxf(bs.z + dc * acc.z, 0.f),
                                   fmaxf(bs.w + dc * acc.w, 0.f));
            if (half == 0) {
                ushort4 o = make_ushort4(f2bf(x.x), f2bf(x.y), f2bf(x.z), f2bf(x.w));
                *(ushort4*)&xoutb[(long)node * D + fl * 4] = o;
                if (STATS) {
                    s.x += x.x; s.y += x.y; s.z += x.z; s.w += x.w;
                    s2.x += x.x * x.x; s2.y += x.y * x.y;
                    s2.z += x.z * x.z; s2.w += x.w * x.w;
                }
            }
        }
    }
    if (STATS) {
        __shared__ float4 smS[256], smQ[256];
        smS[threadIdx.x] = s;
        smQ[threadIdx.x] = s2;
        __syncthreads();
        if (threadIdx.x < 32) {
            float4 a = smS[threadIdx.x], q = smQ[threadIdx.x];
#pragma unroll
            for (int w2 = 1; w2 < 4; ++w2) {
                float4 b = smS[w2 * 64 + threadIdx.x], c = smQ[w2 * 64 + threadIdx.x];
                a.x += b.x; a.y += b.y; a.z += b.z; a.w += b.w;
                q.x += c.x; q.y += c.y; q.z += c.z; q.w += c.w;
            }
            int f0 = 4 * threadIdx.x;
            pS[(f0 + 0) * NB + blockIdx.x] = a.x;
            pS[(f0 + 1) * NB + blockIdx.x] = a.y;
            pS[(f0 + 2) * NB + blockIdx.x] = a.z;
            pS[(f0 + 3) * NB + blockIdx.x] = a.w;
            pQ[(f0 + 0) * NB + blockIdx.x] = q.x;
            pQ[(f0 + 1) * NB + blockIdx.x] = q.y;
            pQ[(f0 + 2) * NB + blockIdx.x] = q.z;
            pQ[(f0 + 3) * NB + blockIdx.x] = q.w;
        }
    }
}

// ---------------- softmax pooling (bounds in-block; bf16 x input) ----------------

__global__ __launch_bounds__(1024) void pool_kernel(const float* __restrict__ tfidf,
                                                    const int* __restrict__ batch,
                                                    const unsigned short* __restrict__ xb,
                                                    float* __restrict__ out, int n) {
    int g = blockIdx.x;
    int tid = threadIdx.x;
    __shared__ int sbounds[2];
    if (tid < 2) {
        int target = g + tid;
        int lo = 0, hi = n;
        while (lo < hi) {
            int mid = (lo + hi) >> 1;
            if (batch[mid] < target) lo = mid + 1;
            else hi = mid;
        }
        sbounds[tid] = lo;
    }
    __syncthreads();
    int s0 = sbounds[0], s1 = sbounds[1];
    int d = tid & 127, sub = tid >> 7;
    __shared__ float red[1024];
    float m = -1e30f;
    for (int i = s0 + tid; i < s1; i += 1024) m = fmaxf(m, tfidf[i]);
    red[tid] = m;
    __syncthreads();
    for (int off = 512; off > 0; off >>= 1) {
        if (tid < off) red[tid] = fmaxf(red[tid], red[tid + off]);
        __syncthreads();
    }
    m = red[0];
    __syncthreads();
    float s = 0.f;
    for (int i = s0 + tid; i < s1; i += 1024) s += __expf(tfidf[i] - m);
    red[tid] = s;
    __syncthreads();
    for (int off = 512; off > 0; off >>= 1) {
        if (tid < off) red[tid] += red[tid + off];
        __syncthreads();
    }
    s = red[0];
    __syncthreads();
    float acc = 0.f;
    for (int i = s0 + sub; i < s1; i += 8) {
        float xv = __uint_as_float(((unsigned int)xb[(long)i * D + d]) << 16);
        acc += __expf(tfidf[i] - m) * xv;
    }
    red[tid] = acc;
    __syncthreads();
    if (tid < 128) {
        float a = 0.f;
#pragma unroll
        for (int w = 0; w < 8; ++w) a += red[w * 128 + d];
        out[g * D + d] = (s1 > s0) ? a / s : 0.f;
    }
}

// ---------------- launch ----------------

extern "C" void kernel_launch(void* const* d_in, const int* in_sizes, int n_in, void* d_out,
                              int out_size, void* d_ws, size_t ws_size, hipStream_t stream) {
    const int N = in_sizes[0];
    const int E = in_sizes[4];
    const int G = out_size / D;
    const int BN_GRID = 768;
    const int AGG_GRID = 2048;

    const int* x_index = (const int*)d_in[0];
    const float* tfidf = (const float*)d_in[1];
    const int* ei_row = (const int*)d_in[2];
    const int* ei_col = ei_row + E;
    const int* batch = (const int*)d_in[3];
    const float* edge_attr = (const float*)d_in[4];
    const float* emb = (const float*)d_in[5];
    const float* gamma1 = (const float*)d_in[6];
    const float* beta1 = (const float*)d_in[7];
    const float* W1 = (const float*)d_in[8];
    const float* b1 = (const float*)d_in[9];
    const float* gamma2 = (const float*)d_in[10];
    const float* beta2 = (const float*)d_in[11];
    const float* W2 = (const float*)d_in[12];
    const float* b2 = (const float*)d_in[13];
    float* out = (float*)d_out;

    // ---- workspace carve (256B aligned) ----
    size_t off = 0;
    char* base = (char*)d_ws;
    auto carve = [&](size_t bytes) -> void* {
        void* p = base + off;
        off = (off + bytes + 255) & ~(size_t)255;
        return p;
    };
    unsigned short* bufA = (unsigned short*)carve((size_t)N * D * 2);  // h' (bf16)
    unsigned short* bufB = (unsigned short*)carve((size_t)N * D * 2);  // x (bf16)
    long long* pk = (long long*)carve((size_t)E * 8);                  // packed (row, ea)
    int2* csr = (int2*)carve((size_t)E * 8);                           // (row, ea)
    int* rank = (int*)carve((size_t)E * 4);                            // arrival rank
    int* cnt = (int*)carve((size_t)N * 4);                             // zeroed in prep_w
    float* dis = (float*)carve((size_t)N * 4);
    int* offs = (int*)carve((size_t)(N + 1) * 4);
    float* scale1 = (float*)carve(D * 4);
    float* shift1 = (float*)carve(D * 4);
    float* scale2 = (float*)carve(D * 4);
    float* shift2 = (float*)carve(D * 4);
    unsigned short* WT1b = (unsigned short*)carve((size_t)D * D * 2);
    unsigned short* WT2b = (unsigned short*)carve((size_t)D * D * 2);
    float* pS = (float*)carve((size_t)AGG_GRID * D * 4);
    float* pQ = (float*)carve((size_t)AGG_GRID * D * 4);
    (void)ws_size;
    (void)n_in;

    // ---- W -> bf16 transposed + cnt zeroing ----
    prep_w<<<2 * D, D, 0, stream>>>(W1, W2, WT1b, WT2b, cnt, N);

    // ---- edge preprocessing: CSR (deterministic; shared by both layers) ----
    hist_rank_kernel<<<cdiv(E, 256), 256, 0, stream>>>(ei_col, cnt, rank, E);
    int nb = cdiv(N, 1024);
    scan_kernel<<<nb, 1024, 0, stream>>>(cnt, offs, N, E);
    scatter_pack<<<cdiv(E, 256), 256, 0, stream>>>(ei_row, ei_col, edge_attr, rank, offs, pk,
                                                   E);
    // ---- sort (VALU-bound) overlapped with layer-1 BN stats gather (memory-bound) ----
    int SB = cdiv(N, 4);
    sort_bn_kernel<<<SB + BN_GRID, 256, 0, stream>>>(pk, offs, dis, csr, N, emb, x_index, pS,
                                                     pQ, SB, BN_GRID);

    // ---- layer 1 ----
    bn_reduce<<<D, 256, 0, stream>>>(pS, pQ, BN_GRID, gamma1, beta1, scale1, shift1, (float)N);
    gemm_mfma<true, false><<<cdiv(N, 64), 256, 0, stream>>>(emb, x_index, scale1, shift1, WT1b,
                                                            dis, bufA, N);
    agg_kernel<true><<<AGG_GRID, 256, 0, stream>>>((const uint2*)bufA, csr, offs, dis,
                                                   (const float4*)b1, bufB, N, pS, pQ,
                                                   AGG_GRID);

    // ---- layer 2 ----
    bn_reduce<<<D, 256, 0, stream>>>(pS, pQ, AGG_GRID, gamma2, beta2, scale2, shift2, (float)N);
    gemm_mfma<false, true><<<cdiv(N, 64), 256, 0, stream>>>(bufB, nullptr, scale2, shift2,
                                                            WT2b, dis, bufA, N);
    agg_kernel<false><<<cdiv(N, 4), 256, 0, stream>>>((const uint2*)bufA, csr, offs, dis,
                                                      (const float4*)b2, bufB, N, nullptr,
                                                      nullptr, 0);

    // ---- softmax pooling (bf16 x) ----
    pool_kernel<<<G, 1024, 0, stream>>>(tfidf, batch, bufB, out, N);
}